// Round 1
// baseline (752.436 us; speedup 1.0000x reference)
//
#include <hip/hip_runtime.h>

#define N_NODES 100000
#define N_EDGES 800000
#define DV 64
#define DE 32
#define DU 32
#define H 128
#define K1E 192   // 2*DV + DE + DU
#define K1N 224   // DV + H + DU

typedef short bf16x8 __attribute__((ext_vector_type(8)));
typedef unsigned short u16;
typedef u16 u16x8 __attribute__((ext_vector_type(8)));
typedef float f32x4 __attribute__((ext_vector_type(4)));

// weight buffer layout (u16 elements), after 1024-byte sums header in d_ws
#define W1ET_OFF 0        // [128][192]
#define W2ET_OFF 24576    // [128][128]
#define W1NT_OFF 40960    // [128][224]
#define W2NT_OFF 69632    // [128][128]
#define WBUF_ELEMS 86016

__device__ inline u16 f2bf(float x) {
  union { float f; unsigned u; } c; c.f = x;
  unsigned r = c.u + 0x7FFFu + ((c.u >> 16) & 1u);   // round-to-nearest-even
  return (u16)(r >> 16);
}

__global__ void prep_weights(const float* __restrict__ W1e, const float* __restrict__ W2e,
                             const float* __restrict__ W1n, const float* __restrict__ W2n,
                             u16* __restrict__ wbuf) {
  int i = blockIdx.x * blockDim.x + threadIdx.x;
  if (i < 24576) {                     // W1e^T [128][192]
    int j = i / 192, k = i - j * 192;
    wbuf[W1ET_OFF + i] = f2bf(W1e[k * H + j]);
  } else if (i < 40960) {              // W2e^T [128][128]
    int t = i - 24576; int j = t >> 7, k = t & 127;
    wbuf[i] = f2bf(W2e[k * H + j]);
  } else if (i < 69632) {              // W1n^T [128][224]
    int t = i - 40960; int j = t / 224, k = t - j * 224;
    wbuf[i] = f2bf(W1n[k * H + j]);
  } else if (i < WBUF_ELEMS) {         // W2n^T [128][128]
    int t = i - 69632; int j = t >> 7, k = t & 127;
    wbuf[i] = f2bf(W2n[k * H + j]);
  }
}

// ---------------- edge kernel: 64 edges per block, 4 waves x 32 output cols ----------
__global__ __launch_bounds__(256, 2) void edge_kernel(
    const float* __restrict__ node_attr, const int* __restrict__ edges,
    const float* __restrict__ edge_attr, const float* __restrict__ uattr,
    const int* __restrict__ edge_idx, const u16* __restrict__ wbuf,
    const float* __restrict__ b1, const float* __restrict__ b2,
    float* __restrict__ e_out, float* __restrict__ agg, float* __restrict__ esum)
{
  __shared__ __align__(16) u16 X[64][200];    // 192 cols + pad (stride 400B -> 2-way ok)
  __shared__ __align__(16) u16 Hs[64][136];   // 128 cols + pad
  __shared__ int sSrc[64], sDst[64], sEidx[64];

  const int tid = threadIdx.x;
  const int wave = tid >> 6, lane = tid & 63;
  const int l15 = lane & 15, lg = lane >> 4;
  const long e0 = (long)blockIdx.x * 64;
  const int wc = wave * 32;

  if (tid < 64)        sSrc[tid]        = edges[e0 + tid];
  else if (tid < 128)  sDst[tid - 64]   = edges[(long)N_EDGES + e0 + (tid - 64)];
  else if (tid < 192)  sEidx[tid - 128] = edge_idx[e0 + (tid - 128)];

  // per-wave weight slices in registers
  bf16x8 w1[6][2], w2[4][2];
  {
    const u16* w1t = wbuf + W1ET_OFF;
    const u16* w2t = wbuf + W2ET_OFF;
#pragma unroll
    for (int cf = 0; cf < 2; ++cf) {
      const u16* p1 = w1t + (wc + cf * 16 + l15) * 192 + lg * 8;
#pragma unroll
      for (int ks = 0; ks < 6; ++ks) w1[ks][cf] = *(const bf16x8*)(p1 + ks * 32);
      const u16* p2 = w2t + (wc + cf * 16 + l15) * 128 + lg * 8;
#pragma unroll
      for (int ks = 0; ks < 4; ++ks) w2[ks][cf] = *(const bf16x8*)(p2 + ks * 32);
    }
  }

  __syncthreads();

  // stage X: 64 rows x 192 cols of bf16, 8 cols/chunk -> 1536 chunks, 6 per thread
#pragma unroll
  for (int it = 0; it < 6; ++it) {
    int ch = tid + it * 256;
    int r = ch / 24, seg = ch - r * 24;
    int col = seg * 8;
    const float* src;
    if (col < 64)        src = node_attr + (long)sSrc[r] * DV + col;
    else if (col < 128)  src = node_attr + (long)sDst[r] * DV + (col - 64);
    else if (col < 160)  src = edge_attr + (e0 + r) * DE + (col - 128);
    else                 src = uattr + (long)sEidx[r] * DU + (col - 160);
    float4 f0 = *(const float4*)src;
    float4 f1 = *(const float4*)(src + 4);
    u16x8 p;
    p[0] = f2bf(f0.x); p[1] = f2bf(f0.y); p[2] = f2bf(f0.z); p[3] = f2bf(f0.w);
    p[4] = f2bf(f1.x); p[5] = f2bf(f1.y); p[6] = f2bf(f1.z); p[7] = f2bf(f1.w);
    *(u16x8*)&X[r][col] = p;
  }

  __syncthreads();

  f32x4 acc[4][2];
#pragma unroll
  for (int rf = 0; rf < 4; ++rf)
#pragma unroll
    for (int cf = 0; cf < 2; ++cf)
#pragma unroll
      for (int j = 0; j < 4; ++j) acc[rf][cf][j] = 0.f;

  // layer 1: [64,192] @ [192,128]
#pragma unroll
  for (int ks = 0; ks < 6; ++ks) {
#pragma unroll
    for (int rf = 0; rf < 4; ++rf) {
      bf16x8 a = *(const bf16x8*)&X[rf * 16 + l15][ks * 32 + lg * 8];
      acc[rf][0] = __builtin_amdgcn_mfma_f32_16x16x32_bf16(a, w1[ks][0], acc[rf][0], 0, 0, 0);
      acc[rf][1] = __builtin_amdgcn_mfma_f32_16x16x32_bf16(a, w1[ks][1], acc[rf][1], 0, 0, 0);
    }
  }

  float bias1[2] = { b1[wc + l15], b1[wc + 16 + l15] };
#pragma unroll
  for (int rf = 0; rf < 4; ++rf)
#pragma unroll
    for (int cf = 0; cf < 2; ++cf)
#pragma unroll
      for (int j = 0; j < 4; ++j) {
        float hv = acc[rf][cf][j] + bias1[cf];
        hv = hv > 0.f ? hv : 0.f;
        Hs[rf * 16 + lg * 4 + j][wc + cf * 16 + l15] = f2bf(hv);
      }

  __syncthreads();

#pragma unroll
  for (int rf = 0; rf < 4; ++rf)
#pragma unroll
    for (int cf = 0; cf < 2; ++cf)
#pragma unroll
      for (int j = 0; j < 4; ++j) acc[rf][cf][j] = 0.f;

  // layer 2: [64,128] @ [128,128]
#pragma unroll
  for (int ks = 0; ks < 4; ++ks) {
#pragma unroll
    for (int rf = 0; rf < 4; ++rf) {
      bf16x8 a = *(const bf16x8*)&Hs[rf * 16 + l15][ks * 32 + lg * 8];
      acc[rf][0] = __builtin_amdgcn_mfma_f32_16x16x32_bf16(a, w2[ks][0], acc[rf][0], 0, 0, 0);
      acc[rf][1] = __builtin_amdgcn_mfma_f32_16x16x32_bf16(a, w2[ks][1], acc[rf][1], 0, 0, 0);
    }
  }

  float bias2[2] = { b2[wc + l15], b2[wc + 16 + l15] };
  float es0 = 0.f, es1 = 0.f;
#pragma unroll
  for (int rf = 0; rf < 4; ++rf) {
#pragma unroll
    for (int cf = 0; cf < 2; ++cf) {
      int colg = wc + cf * 16 + l15;
#pragma unroll
      for (int j = 0; j < 4; ++j) {
        int r = rf * 16 + lg * 4 + j;
        float v = acc[rf][cf][j] + bias2[cf];
        e_out[(e0 + r) * H + colg] = v;
        atomicAdd(&agg[(long)sDst[r] * H + colg], v);
        if (cf == 0) es0 += v; else es1 += v;
      }
    }
  }
#pragma unroll
  for (int m = 16; m < 64; m <<= 1) { es0 += __shfl_xor(es0, m); es1 += __shfl_xor(es1, m); }
  if (lane < 16) {
    atomicAdd(&esum[wc + lane], es0);
    atomicAdd(&esum[wc + 16 + lane], es1);
  }
}

// ---------------- node kernel: 64 nodes per block; reads agg from v-region, writes v in place
__global__ __launch_bounds__(256, 2) void node_kernel(
    const float* __restrict__ node_attr, const float* __restrict__ uattr,
    const int* __restrict__ node_idx, const u16* __restrict__ wbuf,
    const float* __restrict__ b1, const float* __restrict__ b2,
    float* __restrict__ vio, float* __restrict__ vsum)
{
  __shared__ __align__(16) u16 X[64][232];    // 224 cols + pad
  __shared__ __align__(16) u16 Hs[64][136];

  const int tid = threadIdx.x;
  const int wave = tid >> 6, lane = tid & 63;
  const int l15 = lane & 15, lg = lane >> 4;
  const long n0 = (long)blockIdx.x * 64;
  const int wc = wave * 32;

  bf16x8 w1[7][2], w2[4][2];
  {
    const u16* w1t = wbuf + W1NT_OFF;
    const u16* w2t = wbuf + W2NT_OFF;
#pragma unroll
    for (int cf = 0; cf < 2; ++cf) {
      const u16* p1 = w1t + (wc + cf * 16 + l15) * 224 + lg * 8;
#pragma unroll
      for (int ks = 0; ks < 7; ++ks) w1[ks][cf] = *(const bf16x8*)(p1 + ks * 32);
      const u16* p2 = w2t + (wc + cf * 16 + l15) * 128 + lg * 8;
#pragma unroll
      for (int ks = 0; ks < 4; ++ks) w2[ks][cf] = *(const bf16x8*)(p2 + ks * 32);
    }
  }

  // stage X: 64 rows x 224 cols -> 1792 chunks, 7 per thread
#pragma unroll
  for (int it = 0; it < 7; ++it) {
    int ch = tid + it * 256;
    int r = ch / 28, seg = ch - r * 28;
    int col = seg * 8;
    long n = n0 + r; if (n >= N_NODES) n = N_NODES - 1;   // clamp tail
    const float* src;
    if (col < 64)        src = node_attr + n * DV + col;
    else if (col < 192)  src = vio + n * H + (col - 64);
    else                 src = uattr + (long)node_idx[n] * DU + (col - 192);
    float4 f0 = *(const float4*)src;
    float4 f1 = *(const float4*)(src + 4);
    u16x8 p;
    p[0] = f2bf(f0.x); p[1] = f2bf(f0.y); p[2] = f2bf(f0.z); p[3] = f2bf(f0.w);
    p[4] = f2bf(f1.x); p[5] = f2bf(f1.y); p[6] = f2bf(f1.z); p[7] = f2bf(f1.w);
    *(u16x8*)&X[r][col] = p;
  }

  __syncthreads();

  f32x4 acc[4][2];
#pragma unroll
  for (int rf = 0; rf < 4; ++rf)
#pragma unroll
    for (int cf = 0; cf < 2; ++cf)
#pragma unroll
      for (int j = 0; j < 4; ++j) acc[rf][cf][j] = 0.f;

#pragma unroll
  for (int ks = 0; ks < 7; ++ks) {
#pragma unroll
    for (int rf = 0; rf < 4; ++rf) {
      bf16x8 a = *(const bf16x8*)&X[rf * 16 + l15][ks * 32 + lg * 8];
      acc[rf][0] = __builtin_amdgcn_mfma_f32_16x16x32_bf16(a, w1[ks][0], acc[rf][0], 0, 0, 0);
      acc[rf][1] = __builtin_amdgcn_mfma_f32_16x16x32_bf16(a, w1[ks][1], acc[rf][1], 0, 0, 0);
    }
  }

  float bias1[2] = { b1[wc + l15], b1[wc + 16 + l15] };
#pragma unroll
  for (int rf = 0; rf < 4; ++rf)
#pragma unroll
    for (int cf = 0; cf < 2; ++cf)
#pragma unroll
      for (int j = 0; j < 4; ++j) {
        float hv = acc[rf][cf][j] + bias1[cf];
        hv = hv > 0.f ? hv : 0.f;
        Hs[rf * 16 + lg * 4 + j][wc + cf * 16 + l15] = f2bf(hv);
      }

  __syncthreads();

#pragma unroll
  for (int rf = 0; rf < 4; ++rf)
#pragma unroll
    for (int cf = 0; cf < 2; ++cf)
#pragma unroll
      for (int j = 0; j < 4; ++j) acc[rf][cf][j] = 0.f;

#pragma unroll
  for (int ks = 0; ks < 4; ++ks) {
#pragma unroll
    for (int rf = 0; rf < 4; ++rf) {
      bf16x8 a = *(const bf16x8*)&Hs[rf * 16 + l15][ks * 32 + lg * 8];
      acc[rf][0] = __builtin_amdgcn_mfma_f32_16x16x32_bf16(a, w2[ks][0], acc[rf][0], 0, 0, 0);
      acc[rf][1] = __builtin_amdgcn_mfma_f32_16x16x32_bf16(a, w2[ks][1], acc[rf][1], 0, 0, 0);
    }
  }

  float bias2[2] = { b2[wc + l15], b2[wc + 16 + l15] };
  float vs0 = 0.f, vs1 = 0.f;
#pragma unroll
  for (int rf = 0; rf < 4; ++rf) {
#pragma unroll
    for (int cf = 0; cf < 2; ++cf) {
      int colg = wc + cf * 16 + l15;
#pragma unroll
      for (int j = 0; j < 4; ++j) {
        int r = rf * 16 + lg * 4 + j;
        long n = n0 + r;
        if (n < N_NODES) {
          float v = acc[rf][cf][j] + bias2[cf];
          vio[n * H + colg] = v;   // in-place overwrite of agg (reads all done pre-barrier)
          if (cf == 0) vs0 += v; else vs1 += v;
        }
      }
    }
  }
#pragma unroll
  for (int m = 16; m < 64; m <<= 1) { vs0 += __shfl_xor(vs0, m); vs1 += __shfl_xor(vs1, m); }
  if (lane < 16) {
    atomicAdd(&vsum[wc + lane], vs0);
    atomicAdd(&vsum[wc + 16 + lane], vs1);
  }
}

// ---------------- global kernel: G=1, f32 precision ----------------
__global__ void global_kernel(const float* __restrict__ uattr,
    const float* __restrict__ W1g, const float* __restrict__ b1g,
    const float* __restrict__ W2g, const float* __restrict__ b2g,
    const float* __restrict__ esum, const float* __restrict__ vsum,
    float* __restrict__ g_out)
{
  __shared__ float gin[288];
  __shared__ float hbuf[128];
  int t = threadIdx.x;   // 128 threads
  gin[t]       = vsum[t] * (1.f / (float)N_NODES);
  gin[128 + t] = esum[t] * (1.f / (float)N_EDGES);
  if (t < 32) gin[256 + t] = uattr[t];
  __syncthreads();
  float a = b1g[t];
  for (int k = 0; k < 288; ++k) a += gin[k] * W1g[k * H + t];
  hbuf[t] = fmaxf(a, 0.f);
  __syncthreads();
  float b = b2g[t];
  for (int k = 0; k < 128; ++k) b += hbuf[k] * W2g[k * H + t];
  g_out[t] = b;
}

extern "C" void kernel_launch(void* const* d_in, const int* in_sizes, int n_in,
                              void* d_out, int out_size, void* d_ws, size_t ws_size,
                              hipStream_t stream) {
  const float* node_attr = (const float*)d_in[0];
  const int*   edges     = (const int*)d_in[1];
  const float* edge_attr = (const float*)d_in[2];
  const float* uattr     = (const float*)d_in[3];
  const int*   node_idx  = (const int*)d_in[4];
  const int*   edge_idx  = (const int*)d_in[5];
  const float* W1e = (const float*)d_in[6];  const float* b1e = (const float*)d_in[7];
  const float* W2e = (const float*)d_in[8];  const float* b2e = (const float*)d_in[9];
  const float* W1n = (const float*)d_in[10]; const float* b1n = (const float*)d_in[11];
  const float* W2n = (const float*)d_in[12]; const float* b2n = (const float*)d_in[13];
  const float* W1g = (const float*)d_in[14]; const float* b1g = (const float*)d_in[15];
  const float* W2g = (const float*)d_in[16]; const float* b2g = (const float*)d_in[17];

  float* out   = (float*)d_out;
  float* v_out = out;                                          // [N,H] (agg scratch first)
  float* e_out = out + (long)N_NODES * H;                      // [E,H]
  float* g_out = out + (long)N_NODES * H + (long)N_EDGES * H;  // [G,H]

  float* esum = (float*)d_ws;          // [128]
  float* vsum = esum + 128;            // [128]
  u16*   wbuf = (u16*)((char*)d_ws + 1024);

  // zero agg accumulator (v region) and the sum header
  hipMemsetAsync(v_out, 0, (size_t)N_NODES * H * sizeof(float), stream);
  hipMemsetAsync(d_ws, 0, 1024, stream);

  prep_weights<<<(WBUF_ELEMS + 255) / 256, 256, 0, stream>>>(W1e, W2e, W1n, W2n, wbuf);
  edge_kernel<<<N_EDGES / 64, 256, 0, stream>>>(node_attr, edges, edge_attr, uattr,
                                                edge_idx, wbuf, b1e, b2e,
                                                e_out, v_out, esum);
  node_kernel<<<(N_NODES + 63) / 64, 256, 0, stream>>>(node_attr, uattr, node_idx,
                                                       wbuf, b1n, b2n, v_out, vsum);
  global_kernel<<<1, 128, 0, stream>>>(uattr, W1g, b1g, W2g, b2g, esum, vsum, g_out);
}

// Round 3
// 619.474 us; speedup vs baseline: 1.2146x; 1.2146x over previous
//
#include <hip/hip_runtime.h>

#define N_NODES 100000
#define N_EDGES 800000
#define DV 64
#define DE 32
#define DU 32
#define H 128

typedef short bf16x8 __attribute__((ext_vector_type(8)));
typedef unsigned short u16;
typedef u16 u16x8 __attribute__((ext_vector_type(8)));
typedef float f32x4 __attribute__((ext_vector_type(4)));

// ---- workspace layout (bytes) ----
#define OFF_ESUM 0            // [128][16] f32 padded sums (one cacheline per col)
#define OFF_VSUM 8192         // [128][16] f32
#define OFF_PART 16384        // [512] int scan partials
#define OFF_WBUF 18432        // [86016] u16 weights
#define OFF_DEG  190464       // [100000] int degree -> cursor
#define OFF_OFFS 590464       // [100000] int CSR row starts
#define OFF_BUCK 990464       // [800000] int edge ids grouped by dst
// total ~4.19 MB

// weight sub-offsets (u16 elements within wbuf)
#define W1ET_OFF 0            // [128][192]
#define W2ET_OFF 24576        // [128][128]
#define W1NT_OFF 40960        // [128][224]
#define W2NT_OFF 69632        // [128][128]
#define WBUF_ELEMS 86016

#define NPART 391             // ceil(100000/256)

__device__ inline u16 f2bf(float x) {
  union { float f; unsigned u; } c; c.f = x;
  unsigned r = c.u + 0x7FFFu + ((c.u >> 16) & 1u);   // round-to-nearest-even
  return (u16)(r >> 16);
}

__global__ void prep_weights(const float* __restrict__ W1e, const float* __restrict__ W2e,
                             const float* __restrict__ W1n, const float* __restrict__ W2n,
                             u16* __restrict__ wbuf) {
  int i = blockIdx.x * blockDim.x + threadIdx.x;
  if (i < 24576) {                     // W1e^T [128][192]
    int j = i / 192, k = i - j * 192;
    wbuf[W1ET_OFF + i] = f2bf(W1e[k * H + j]);
  } else if (i < 40960) {              // W2e^T [128][128]
    int t = i - 24576; int j = t >> 7, k = t & 127;
    wbuf[i] = f2bf(W2e[k * H + j]);
  } else if (i < 69632) {              // W1n^T [128][224]
    int t = i - 40960; int j = t / 224, k = t - j * 224;
    wbuf[i] = f2bf(W1n[k * H + j]);
  } else if (i < WBUF_ELEMS) {         // W2n^T [128][128]
    int t = i - 69632; int j = t >> 7, k = t & 127;
    wbuf[i] = f2bf(W2n[k * H + j]);
  }
}

// ---------------- CSR build ----------------
__global__ void degree_kernel(const int* __restrict__ edges, int* __restrict__ deg) {
  int i = blockIdx.x * 256 + threadIdx.x;
  if (i < N_EDGES) atomicAdd(&deg[edges[N_EDGES + i]], 1);
}

__global__ void scan_part(const int* __restrict__ deg, int* __restrict__ part) {
  int i = blockIdx.x * 256 + threadIdx.x;
  int v = (i < N_NODES) ? deg[i] : 0;
#pragma unroll
  for (int m = 1; m < 64; m <<= 1) v += __shfl_xor(v, m);
  __shared__ int s[4];
  if ((threadIdx.x & 63) == 0) s[threadIdx.x >> 6] = v;
  __syncthreads();
  if (threadIdx.x == 0) part[blockIdx.x] = s[0] + s[1] + s[2] + s[3];
}

__global__ void scan_top(int* __restrict__ part) {
  __shared__ int s[512];
  int t = threadIdx.x;
  s[t] = (t < NPART) ? part[t] : 0;
  __syncthreads();
  for (int d = 1; d < 512; d <<= 1) {
    int v = (t >= d) ? s[t - d] : 0;
    __syncthreads();
    s[t] += v;
    __syncthreads();
  }
  if (t < NPART) part[t] = (t == 0) ? 0 : s[t - 1];   // exclusive
}

__global__ void scan_down(const int* __restrict__ part, int* __restrict__ deg_cursor,
                          int* __restrict__ offsets) {
  __shared__ int s[256];
  int b = blockIdx.x, t = threadIdx.x;
  int i = b * 256 + t;
  int v = (i < N_NODES) ? deg_cursor[i] : 0;
  s[t] = v;
  __syncthreads();
  for (int d = 1; d < 256; d <<= 1) {
    int u = (t >= d) ? s[t - d] : 0;
    __syncthreads();
    s[t] += u;
    __syncthreads();
  }
  int excl = s[t] - v + part[b];
  if (i < N_NODES) { offsets[i] = excl; deg_cursor[i] = excl; }  // cursor = start
}

__global__ void fill_kernel(const int* __restrict__ edges, int* __restrict__ cursor,
                            int* __restrict__ bucket) {
  int i = blockIdx.x * 256 + threadIdx.x;
  if (i < N_EDGES) {
    int d = edges[N_EDGES + i];
    int pos = atomicAdd(&cursor[d], 1);
    bucket[pos] = i;
  }
}

// ---------------- edge kernel: 64 edges/block, 4 waves x 32 output cols ----------
__global__ __launch_bounds__(256, 3) void edge_kernel(
    const float* __restrict__ node_attr, const int* __restrict__ edges,
    const float* __restrict__ edge_attr, const float* __restrict__ uattr,
    const int* __restrict__ edge_idx, const u16* __restrict__ wbuf,
    const float* __restrict__ b1, const float* __restrict__ b2,
    float* __restrict__ e_out, float* __restrict__ esum_p)
{
  __shared__ __align__(16) char smem[43008];
  u16 (*X)[200]   = (u16(*)[200])smem;               // 25600 B
  u16 (*Hs)[136]  = (u16(*)[136])(smem + 25600);     // 17408 B
  float (*OT)[132] = (float(*)[132])smem;            // 33792 B (reuses X+Hs after MFMA)
  __shared__ int sSrc[64], sDst[64], sEidx[64];

  const int tid = threadIdx.x;
  const int wave = tid >> 6, lane = tid & 63;
  const int l15 = lane & 15, lg = lane >> 4;
  const long e0 = (long)blockIdx.x * 64;
  const int wc = wave * 32;

  if (tid < 64)        sSrc[tid]        = edges[e0 + tid];
  else if (tid < 128)  sDst[tid - 64]   = edges[(long)N_EDGES + e0 + (tid - 64)];
  else if (tid < 192)  sEidx[tid - 128] = edge_idx[e0 + (tid - 128)];

  // per-wave weight slices in registers
  bf16x8 w1[6][2], w2[4][2];
  {
    const u16* w1t = wbuf + W1ET_OFF;
    const u16* w2t = wbuf + W2ET_OFF;
#pragma unroll
    for (int cf = 0; cf < 2; ++cf) {
      const u16* p1 = w1t + (wc + cf * 16 + l15) * 192 + lg * 8;
#pragma unroll
      for (int ks = 0; ks < 6; ++ks) w1[ks][cf] = *(const bf16x8*)(p1 + ks * 32);
      const u16* p2 = w2t + (wc + cf * 16 + l15) * 128 + lg * 8;
#pragma unroll
      for (int ks = 0; ks < 4; ++ks) w2[ks][cf] = *(const bf16x8*)(p2 + ks * 32);
    }
  }

  __syncthreads();

  // stage X: 64 rows x 192 cols of bf16 -> 1536 chunks, 6/thread
#pragma unroll
  for (int it = 0; it < 6; ++it) {
    int ch = tid + it * 256;
    int r = ch / 24, seg = ch - r * 24;
    int col = seg * 8;
    const float* src;
    if (col < 64)        src = node_attr + (long)sSrc[r] * DV + col;
    else if (col < 128)  src = node_attr + (long)sDst[r] * DV + (col - 64);
    else if (col < 160)  src = edge_attr + (e0 + r) * DE + (col - 128);
    else                 src = uattr + (long)sEidx[r] * DU + (col - 160);
    float4 f0 = *(const float4*)src;
    float4 f1 = *(const float4*)(src + 4);
    u16x8 p;
    p[0] = f2bf(f0.x); p[1] = f2bf(f0.y); p[2] = f2bf(f0.z); p[3] = f2bf(f0.w);
    p[4] = f2bf(f1.x); p[5] = f2bf(f1.y); p[6] = f2bf(f1.z); p[7] = f2bf(f1.w);
    *(u16x8*)&X[r][col] = p;
  }

  __syncthreads();

  f32x4 acc[4][2];
#pragma unroll
  for (int rf = 0; rf < 4; ++rf)
#pragma unroll
    for (int cf = 0; cf < 2; ++cf)
#pragma unroll
      for (int j = 0; j < 4; ++j) acc[rf][cf][j] = 0.f;

  // layer 1: [64,192] @ [192,128]
#pragma unroll
  for (int ks = 0; ks < 6; ++ks) {
#pragma unroll
    for (int rf = 0; rf < 4; ++rf) {
      bf16x8 a = *(const bf16x8*)&X[rf * 16 + l15][ks * 32 + lg * 8];
      acc[rf][0] = __builtin_amdgcn_mfma_f32_16x16x32_bf16(a, w1[ks][0], acc[rf][0], 0, 0, 0);
      acc[rf][1] = __builtin_amdgcn_mfma_f32_16x16x32_bf16(a, w1[ks][1], acc[rf][1], 0, 0, 0);
    }
  }

  float bias1[2] = { b1[wc + l15], b1[wc + 16 + l15] };
#pragma unroll
  for (int rf = 0; rf < 4; ++rf)
#pragma unroll
    for (int cf = 0; cf < 2; ++cf)
#pragma unroll
      for (int j = 0; j < 4; ++j) {
        float hv = acc[rf][cf][j] + bias1[cf];
        hv = hv > 0.f ? hv : 0.f;
        Hs[rf * 16 + lg * 4 + j][wc + cf * 16 + l15] = f2bf(hv);
      }

  __syncthreads();

#pragma unroll
  for (int rf = 0; rf < 4; ++rf)
#pragma unroll
    for (int cf = 0; cf < 2; ++cf)
#pragma unroll
      for (int j = 0; j < 4; ++j) acc[rf][cf][j] = 0.f;

  // layer 2: [64,128] @ [128,128]
#pragma unroll
  for (int ks = 0; ks < 4; ++ks) {
#pragma unroll
    for (int rf = 0; rf < 4; ++rf) {
      bf16x8 a = *(const bf16x8*)&Hs[rf * 16 + l15][ks * 32 + lg * 8];
      acc[rf][0] = __builtin_amdgcn_mfma_f32_16x16x32_bf16(a, w2[ks][0], acc[rf][0], 0, 0, 0);
      acc[rf][1] = __builtin_amdgcn_mfma_f32_16x16x32_bf16(a, w2[ks][1], acc[rf][1], 0, 0, 0);
    }
  }

  __syncthreads();   // all Hs reads done before OT overwrites the same LDS

  float bias2[2] = { b2[wc + l15], b2[wc + 16 + l15] };
  float es0 = 0.f, es1 = 0.f;
#pragma unroll
  for (int rf = 0; rf < 4; ++rf) {
#pragma unroll
    for (int cf = 0; cf < 2; ++cf) {
#pragma unroll
      for (int j = 0; j < 4; ++j) {
        float v = acc[rf][cf][j] + bias2[cf];
        OT[rf * 16 + lg * 4 + j][wc + cf * 16 + l15] = v;
        if (cf == 0) es0 += v; else es1 += v;
      }
    }
  }

  __syncthreads();

  // coalesced store: 2048 float4 chunks, 8/thread, 1KB contiguous per wave-instr
#pragma unroll
  for (int i = 0; i < 8; ++i) {
    int ch = tid + i * 256;
    int r = ch >> 5, c4 = ch & 31;
    float4 f = *(const float4*)&OT[r][c4 * 4];
    *(float4*)(e_out + (e0 + r) * H + c4 * 4) = f;
  }

#pragma unroll
  for (int m = 16; m < 64; m <<= 1) { es0 += __shfl_xor(es0, m); es1 += __shfl_xor(es1, m); }
  if (lane < 16) {
    atomicAdd(&esum_p[(wc + lane) * 16], es0);         // one cacheline per column
    atomicAdd(&esum_p[(wc + 16 + lane) * 16], es1);
  }
}

// ---------------- node kernel: 64 nodes/block; CSR gather-aggregate, no atomics ---
__global__ __launch_bounds__(256, 3) void node_kernel(
    const float* __restrict__ node_attr, const float* __restrict__ uattr,
    const int* __restrict__ node_idx, const u16* __restrict__ wbuf,
    const float* __restrict__ b1, const float* __restrict__ b2,
    const float* __restrict__ e_out, const int* __restrict__ offsets,
    const int* __restrict__ cursor, const int* __restrict__ bucket,
    float* __restrict__ v_out, float* __restrict__ vsum_p)
{
  __shared__ __align__(16) u16 X[64][232];    // 224 cols + pad
  __shared__ __align__(16) u16 Hs[64][136];

  const int tid = threadIdx.x;
  const int wave = tid >> 6, lane = tid & 63;
  const int l15 = lane & 15, lg = lane >> 4;
  const long n0 = (long)blockIdx.x * 64;
  const int wc = wave * 32;

  // ---- CSR gather: 4 threads per node, each sums a 32-float quarter of agg ----
  {
    int gr = tid >> 2, gq = tid & 3;
    long gn = n0 + gr;
    float a[32];
#pragma unroll
    for (int k = 0; k < 32; ++k) a[k] = 0.f;
    if (gn < N_NODES) {
      int s = offsets[gn], e = cursor[gn];     // cursor == row end after fill
      for (int i = s; i < e; ++i) {
        int eid = bucket[i];
        const float* p = e_out + (long)eid * H + gq * 32;
#pragma unroll
        for (int k = 0; k < 8; ++k) {
          float4 f = *(const float4*)(p + k * 4);
          a[k * 4 + 0] += f.x; a[k * 4 + 1] += f.y;
          a[k * 4 + 2] += f.z; a[k * 4 + 3] += f.w;
        }
      }
    }
#pragma unroll
    for (int k = 0; k < 4; ++k) {
      u16x8 pk;
#pragma unroll
      for (int j = 0; j < 8; ++j) pk[j] = f2bf(a[k * 8 + j]);
      *(u16x8*)&X[gr][64 + gq * 32 + k * 8] = pk;
    }
  }

  // ---- stage node_attr (cols 0..63) and u (cols 192..223): 768 chunks, 3/thread ----
#pragma unroll
  for (int it = 0; it < 3; ++it) {
    int ch = tid + it * 256;
    int r = ch / 12, seg = ch - r * 12;
    long n = n0 + r; if (n >= N_NODES) n = N_NODES - 1;
    const float* src;
    int col;
    if (seg < 8) { col = seg * 8;            src = node_attr + n * DV + col; }
    else         { col = 192 + (seg - 8) * 8; src = uattr + (long)node_idx[n] * DU + (seg - 8) * 8; }
    float4 f0 = *(const float4*)src;
    float4 f1 = *(const float4*)(src + 4);
    u16x8 p;
    p[0] = f2bf(f0.x); p[1] = f2bf(f0.y); p[2] = f2bf(f0.z); p[3] = f2bf(f0.w);
    p[4] = f2bf(f1.x); p[5] = f2bf(f1.y); p[6] = f2bf(f1.z); p[7] = f2bf(f1.w);
    *(u16x8*)&X[r][col] = p;
  }

  // per-wave weight slices
  bf16x8 w1[7][2], w2[4][2];
  {
    const u16* w1t = wbuf + W1NT_OFF;
    const u16* w2t = wbuf + W2NT_OFF;
#pragma unroll
    for (int cf = 0; cf < 2; ++cf) {
      const u16* p1 = w1t + (wc + cf * 16 + l15) * 224 + lg * 8;
#pragma unroll
      for (int ks = 0; ks < 7; ++ks) w1[ks][cf] = *(const bf16x8*)(p1 + ks * 32);
      const u16* p2 = w2t + (wc + cf * 16 + l15) * 128 + lg * 8;
#pragma unroll
      for (int ks = 0; ks < 4; ++ks) w2[ks][cf] = *(const bf16x8*)(p2 + ks * 32);
    }
  }

  __syncthreads();

  f32x4 acc[4][2];
#pragma unroll
  for (int rf = 0; rf < 4; ++rf)
#pragma unroll
    for (int cf = 0; cf < 2; ++cf)
#pragma unroll
      for (int j = 0; j < 4; ++j) acc[rf][cf][j] = 0.f;

#pragma unroll
  for (int ks = 0; ks < 7; ++ks) {
#pragma unroll
    for (int rf = 0; rf < 4; ++rf) {
      bf16x8 a = *(const bf16x8*)&X[rf * 16 + l15][ks * 32 + lg * 8];
      acc[rf][0] = __builtin_amdgcn_mfma_f32_16x16x32_bf16(a, w1[ks][0], acc[rf][0], 0, 0, 0);
      acc[rf][1] = __builtin_amdgcn_mfma_f32_16x16x32_bf16(a, w1[ks][1], acc[rf][1], 0, 0, 0);
    }
  }

  float bias1[2] = { b1[wc + l15], b1[wc + 16 + l15] };
#pragma unroll
  for (int rf = 0; rf < 4; ++rf)
#pragma unroll
    for (int cf = 0; cf < 2; ++cf)
#pragma unroll
      for (int j = 0; j < 4; ++j) {
        float hv = acc[rf][cf][j] + bias1[cf];
        hv = hv > 0.f ? hv : 0.f;
        Hs[rf * 16 + lg * 4 + j][wc + cf * 16 + l15] = f2bf(hv);
      }

  __syncthreads();

#pragma unroll
  for (int rf = 0; rf < 4; ++rf)
#pragma unroll
    for (int cf = 0; cf < 2; ++cf)
#pragma unroll
      for (int j = 0; j < 4; ++j) acc[rf][cf][j] = 0.f;

#pragma unroll
  for (int ks = 0; ks < 4; ++ks) {
#pragma unroll
    for (int rf = 0; rf < 4; ++rf) {
      bf16x8 a = *(const bf16x8*)&Hs[rf * 16 + l15][ks * 32 + lg * 8];
      acc[rf][0] = __builtin_amdgcn_mfma_f32_16x16x32_bf16(a, w2[ks][0], acc[rf][0], 0, 0, 0);
      acc[rf][1] = __builtin_amdgcn_mfma_f32_16x16x32_bf16(a, w2[ks][1], acc[rf][1], 0, 0, 0);
    }
  }

  float bias2[2] = { b2[wc + l15], b2[wc + 16 + l15] };
  float vs0 = 0.f, vs1 = 0.f;
#pragma unroll
  for (int rf = 0; rf < 4; ++rf) {
#pragma unroll
    for (int cf = 0; cf < 2; ++cf) {
      int colg = wc + cf * 16 + l15;
#pragma unroll
      for (int j = 0; j < 4; ++j) {
        int r = rf * 16 + lg * 4 + j;
        long n = n0 + r;
        if (n < N_NODES) {
          float v = acc[rf][cf][j] + bias2[cf];
          v_out[n * H + colg] = v;
          if (cf == 0) vs0 += v; else vs1 += v;
        }
      }
    }
  }
#pragma unroll
  for (int m = 16; m < 64; m <<= 1) { vs0 += __shfl_xor(vs0, m); vs1 += __shfl_xor(vs1, m); }
  if (lane < 16) {
    atomicAdd(&vsum_p[(wc + lane) * 16], vs0);
    atomicAdd(&vsum_p[(wc + 16 + lane) * 16], vs1);
  }
}

// ---------------- global kernel: G=1, f32 precision ----------------
__global__ void global_kernel(const float* __restrict__ uattr,
    const float* __restrict__ W1g, const float* __restrict__ b1g,
    const float* __restrict__ W2g, const float* __restrict__ b2g,
    const float* __restrict__ esum_p, const float* __restrict__ vsum_p,
    float* __restrict__ g_out)
{
  __shared__ float gin[288];
  __shared__ float hbuf[128];
  int t = threadIdx.x;   // 128 threads
  gin[t]       = vsum_p[t * 16] * (1.f / (float)N_NODES);
  gin[128 + t] = esum_p[t * 16] * (1.f / (float)N_EDGES);
  if (t < 32) gin[256 + t] = uattr[t];
  __syncthreads();
  float a = b1g[t];
  for (int k = 0; k < 288; ++k) a += gin[k] * W1g[k * H + t];
  hbuf[t] = fmaxf(a, 0.f);
  __syncthreads();
  float b = b2g[t];
  for (int k = 0; k < 128; ++k) b += hbuf[k] * W2g[k * H + t];
  g_out[t] = b;
}

extern "C" void kernel_launch(void* const* d_in, const int* in_sizes, int n_in,
                              void* d_out, int out_size, void* d_ws, size_t ws_size,
                              hipStream_t stream) {
  const float* node_attr = (const float*)d_in[0];
  const int*   edges     = (const int*)d_in[1];
  const float* edge_attr = (const float*)d_in[2];
  const float* uattr     = (const float*)d_in[3];
  const int*   node_idx  = (const int*)d_in[4];
  const int*   edge_idx  = (const int*)d_in[5];
  const float* W1e = (const float*)d_in[6];  const float* b1e = (const float*)d_in[7];
  const float* W2e = (const float*)d_in[8];  const float* b2e = (const float*)d_in[9];
  const float* W1n = (const float*)d_in[10]; const float* b1n = (const float*)d_in[11];
  const float* W2n = (const float*)d_in[12]; const float* b2n = (const float*)d_in[13];
  const float* W1g = (const float*)d_in[14]; const float* b1g = (const float*)d_in[15];
  const float* W2g = (const float*)d_in[16]; const float* b2g = (const float*)d_in[17];

  float* out   = (float*)d_out;
  float* v_out = out;                                          // [N,H]
  float* e_out = out + (long)N_NODES * H;                      // [E,H]
  float* g_out = out + (long)N_NODES * H + (long)N_EDGES * H;  // [G,H]

  char* ws = (char*)d_ws;
  float* esum_p = (float*)(ws + OFF_ESUM);
  float* vsum_p = (float*)(ws + OFF_VSUM);
  int*   part   = (int*)(ws + OFF_PART);
  u16*   wbuf   = (u16*)(ws + OFF_WBUF);
  int*   deg    = (int*)(ws + OFF_DEG);     // becomes cursor after scan_down
  int*   offs   = (int*)(ws + OFF_OFFS);
  int*   buck   = (int*)(ws + OFF_BUCK);

  hipMemsetAsync(ws, 0, 16384, stream);                  // esum_p + vsum_p
  hipMemsetAsync(deg, 0, N_NODES * sizeof(int), stream); // degrees

  prep_weights<<<WBUF_ELEMS / 256, 256, 0, stream>>>(W1e, W2e, W1n, W2n, wbuf);
  degree_kernel<<<(N_EDGES + 255) / 256, 256, 0, stream>>>(edges, deg);
  scan_part<<<NPART, 256, 0, stream>>>(deg, part);
  scan_top<<<1, 512, 0, stream>>>(part);
  scan_down<<<NPART, 256, 0, stream>>>(part, deg, offs);
  fill_kernel<<<(N_EDGES + 255) / 256, 256, 0, stream>>>(edges, deg, buck);

  edge_kernel<<<N_EDGES / 64, 256, 0, stream>>>(node_attr, edges, edge_attr, uattr,
                                                edge_idx, wbuf, b1e, b2e,
                                                e_out, esum_p);
  node_kernel<<<(N_NODES + 63) / 64, 256, 0, stream>>>(node_attr, uattr, node_idx,
                                                       wbuf, b1n, b2n,
                                                       e_out, offs, deg, buck,
                                                       v_out, vsum_p);
  global_kernel<<<1, 128, 0, stream>>>(uattr, W1g, b1g, W2g, b2g, esum_p, vsum_p, g_out);
}

// Round 4
// 609.910 us; speedup vs baseline: 1.2337x; 1.0157x over previous
//
#include <hip/hip_runtime.h>

#define N_NODES 100000
#define N_EDGES 800000
#define DV 64
#define DE 32
#define DU 32
#define H 128

#define NTILES 12500      // N_EDGES / 64
#define EGRID  512        // persistent edge blocks (2 per CU)

typedef short bf16x8 __attribute__((ext_vector_type(8)));
typedef unsigned short u16;
typedef u16 u16x8 __attribute__((ext_vector_type(8)));
typedef float f32x4 __attribute__((ext_vector_type(4)));

// ---- workspace layout (bytes) ----
#define OFF_ESUM 0            // [128][16] f32 padded sums
#define OFF_VSUM 8192         // [128][16] f32
#define OFF_PART 16384        // [512] int scan partials
#define OFF_WBUF 18432        // [86016] u16 weights
#define OFF_DEG  190464       // [100000] int degree -> cursor
#define OFF_OFFS 590464       // [100000] int CSR row starts
#define OFF_BUCK 990464       // [800000] int edge ids grouped by dst

// weight sub-offsets (u16 elements within wbuf)
#define W1ET_OFF 0            // [128][192]
#define W2ET_OFF 24576        // [128][128]
#define W1NT_OFF 40960        // [128][224]
#define W2NT_OFF 69632        // [128][128]
#define WBUF_ELEMS 86016

#define NPART 391             // ceil(100000/256)

__device__ inline u16 f2bf(float x) {
  union { float f; unsigned u; } c; c.f = x;
  unsigned r = c.u + 0x7FFFu + ((c.u >> 16) & 1u);   // round-to-nearest-even
  return (u16)(r >> 16);
}

// raw barrier: publish LDS writes without draining vmcnt (keeps gathers in flight)
__device__ inline void bar_lgkm() {
  asm volatile("s_waitcnt lgkmcnt(0)" ::: "memory");
  __builtin_amdgcn_sched_barrier(0);
  __builtin_amdgcn_s_barrier();
}

__global__ void prep_weights(const float* __restrict__ W1e, const float* __restrict__ W2e,
                             const float* __restrict__ W1n, const float* __restrict__ W2n,
                             u16* __restrict__ wbuf) {
  int i = blockIdx.x * blockDim.x + threadIdx.x;
  if (i < 24576) {                     // W1e^T [128][192]
    int j = i / 192, k = i - j * 192;
    wbuf[W1ET_OFF + i] = f2bf(W1e[k * H + j]);
  } else if (i < 40960) {              // W2e^T [128][128]
    int t = i - 24576; int j = t >> 7, k = t & 127;
    wbuf[i] = f2bf(W2e[k * H + j]);
  } else if (i < 69632) {              // W1n^T [128][224]
    int t = i - 40960; int j = t / 224, k = t - j * 224;
    wbuf[i] = f2bf(W1n[k * H + j]);
  } else if (i < WBUF_ELEMS) {         // W2n^T [128][128]
    int t = i - 69632; int j = t >> 7, k = t & 127;
    wbuf[i] = f2bf(W2n[k * H + j]);
  }
}

// ---------------- CSR build ----------------
__global__ void degree_kernel(const int* __restrict__ edges, int* __restrict__ deg) {
  int i = blockIdx.x * 256 + threadIdx.x;
  if (i < N_EDGES) atomicAdd(&deg[edges[N_EDGES + i]], 1);
}

__global__ void scan_part(const int* __restrict__ deg, int* __restrict__ part) {
  int i = blockIdx.x * 256 + threadIdx.x;
  int v = (i < N_NODES) ? deg[i] : 0;
#pragma unroll
  for (int m = 1; m < 64; m <<= 1) v += __shfl_xor(v, m);
  __shared__ int s[4];
  if ((threadIdx.x & 63) == 0) s[threadIdx.x >> 6] = v;
  __syncthreads();
  if (threadIdx.x == 0) part[blockIdx.x] = s[0] + s[1] + s[2] + s[3];
}

__global__ void scan_top(int* __restrict__ part) {
  __shared__ int s[512];
  int t = threadIdx.x;
  s[t] = (t < NPART) ? part[t] : 0;
  __syncthreads();
  for (int d = 1; d < 512; d <<= 1) {
    int v = (t >= d) ? s[t - d] : 0;
    __syncthreads();
    s[t] += v;
    __syncthreads();
  }
  if (t < NPART) part[t] = (t == 0) ? 0 : s[t - 1];   // exclusive
}

__global__ void scan_down(const int* __restrict__ part, int* __restrict__ deg_cursor,
                          int* __restrict__ offsets) {
  __shared__ int s[256];
  int b = blockIdx.x, t = threadIdx.x;
  int i = b * 256 + t;
  int v = (i < N_NODES) ? deg_cursor[i] : 0;
  s[t] = v;
  __syncthreads();
  for (int d = 1; d < 256; d <<= 1) {
    int u = (t >= d) ? s[t - d] : 0;
    __syncthreads();
    s[t] += u;
    __syncthreads();
  }
  int excl = s[t] - v + part[b];
  if (i < N_NODES) { offsets[i] = excl; deg_cursor[i] = excl; }  // cursor = start
}

__global__ void fill_kernel(const int* __restrict__ edges, int* __restrict__ cursor,
                            int* __restrict__ bucket) {
  int i = blockIdx.x * 256 + threadIdx.x;
  if (i < N_EDGES) {
    int d = edges[N_EDGES + i];
    int pos = atomicAdd(&cursor[d], 1);
    bucket[pos] = i;
  }
}

// ---------------- edge kernel: persistent, 2-deep pipelined tiles of 64 edges ----
__global__ __launch_bounds__(256, 2) void edge_kernel(
    const float* __restrict__ node_attr, const int* __restrict__ edges,
    const float* __restrict__ edge_attr, const float* __restrict__ uattr,
    const int* __restrict__ edge_idx, const u16* __restrict__ wbuf,
    const float* __restrict__ b1, const float* __restrict__ b2,
    float* __restrict__ e_out, float* __restrict__ esum_p)
{
  __shared__ __align__(16) char smem[43008];
  u16 (*X)[200]    = (u16(*)[200])smem;               // 25600 B
  u16 (*Hs)[136]   = (u16(*)[136])(smem + 25600);     // 17408 B
  float (*OT)[132] = (float(*)[132])smem;             // 33792 B (reuses X+Hs after MFMA)
  __shared__ int sIdx[2][3][64];                      // [buf][src/dst/eidx][64]

  const int tid = threadIdx.x;
  const int lane = tid & 63;
  const int wave = tid >> 6;
  const int l15 = lane & 15, lg = lane >> 4;
  const int wc = wave * 32;
  const int bid = blockIdx.x;

  // per-thread staging geometry (6 chunks of 8 cols)
  int r_[6], c_[6];
#pragma unroll
  for (int it = 0; it < 6; ++it) {
    int ch = tid + it * 256;
    r_[it] = ch / 24;
    c_[it] = (ch - r_[it] * 24) * 8;
  }

  // per-wave weight slices + biases in registers (loaded once per block)
  bf16x8 w1[6][2], w2[4][2];
  {
    const u16* w1t = wbuf + W1ET_OFF;
    const u16* w2t = wbuf + W2ET_OFF;
#pragma unroll
    for (int cf = 0; cf < 2; ++cf) {
      const u16* p1 = w1t + (wc + cf * 16 + l15) * 192 + lg * 8;
#pragma unroll
      for (int ks = 0; ks < 6; ++ks) w1[ks][cf] = *(const bf16x8*)(p1 + ks * 32);
      const u16* p2 = w2t + (wc + cf * 16 + l15) * 128 + lg * 8;
#pragma unroll
      for (int ks = 0; ks < 4; ++ks) w2[ks][cf] = *(const bf16x8*)(p2 + ks * 32);
    }
  }
  float bias1[2] = { b1[wc + l15], b1[wc + 16 + l15] };
  float bias2[2] = { b2[wc + l15], b2[wc + 16 + l15] };

  const int nt = (NTILES - 1 - bid) / EGRID + 1;   // tiles for this block

  float4 G[12];          // in-flight gathered tile (regs)
  int gi = 0;            // in-flight idx element

  auto IDX_LOAD = [&](long t) {
    if (tid < 64)        gi = edges[t * 64 + tid];
    else if (tid < 128)  gi = edges[(long)N_EDGES + t * 64 + (tid - 64)];
    else if (tid < 192)  gi = edge_idx[t * 64 + (tid - 128)];
  };
  auto IDX_WRITE = [&](int buf) {
    if (tid < 64)        sIdx[buf][0][tid] = gi;
    else if (tid < 128)  sIdx[buf][1][tid - 64] = gi;
    else if (tid < 192)  sIdx[buf][2][tid - 128] = gi;
  };
  auto ISSUE = [&](long t, int buf) {
    long e0c = t * 64;
#pragma unroll
    for (int it = 0; it < 6; ++it) {
      int r = r_[it], col = c_[it];
      const float* src;
      if (col < 64)       src = node_attr + (long)sIdx[buf][0][r] * DV + col;
      else if (col < 128) src = node_attr + (long)sIdx[buf][1][r] * DV + (col - 64);
      else if (col < 160) src = edge_attr + (e0c + r) * DE + (col - 128);
      else                src = uattr + (long)sIdx[buf][2][r] * DU + (col - 160);
      G[it * 2]     = *(const float4*)src;
      G[it * 2 + 1] = *(const float4*)(src + 4);
    }
  };
  auto WRITE_X = [&]() {
#pragma unroll
    for (int it = 0; it < 6; ++it) {
      float4 f0 = G[it * 2], f1 = G[it * 2 + 1];
      u16x8 p;
      p[0] = f2bf(f0.x); p[1] = f2bf(f0.y); p[2] = f2bf(f0.z); p[3] = f2bf(f0.w);
      p[4] = f2bf(f1.x); p[5] = f2bf(f1.y); p[6] = f2bf(f1.z); p[7] = f2bf(f1.w);
      *(u16x8*)&X[r_[it]][c_[it]] = p;
    }
  };

  // ---- prologue: fill X(t0), start gathers for t0+EGRID ----
  IDX_LOAD((long)bid);
  IDX_WRITE(0);
  bar_lgkm();
  ISSUE((long)bid, 0);
  if (nt > 1) IDX_LOAD((long)bid + EGRID);
  WRITE_X();
  if (nt > 1) IDX_WRITE(1);
  bar_lgkm();
  if (nt > 1) ISSUE((long)bid + EGRID, 1);

  float es0 = 0.f, es1 = 0.f;

  for (int ti = 0; ti < nt; ++ti) {
    long t = (long)bid + (long)ti * EGRID;
    const bool hasN1 = (ti + 1 < nt);
    const bool hasN2 = (ti + 2 < nt);

    if (hasN2) IDX_LOAD(t + 2 * EGRID);     // early issue, lands this iteration

    f32x4 acc[4][2];
#pragma unroll
    for (int rf = 0; rf < 4; ++rf)
#pragma unroll
      for (int cf = 0; cf < 2; ++cf)
#pragma unroll
        for (int j = 0; j < 4; ++j) acc[rf][cf][j] = 0.f;

    // layer 1: [64,192] @ [192,128]
#pragma unroll
    for (int ks = 0; ks < 6; ++ks) {
#pragma unroll
      for (int rf = 0; rf < 4; ++rf) {
        bf16x8 a = *(const bf16x8*)&X[rf * 16 + l15][ks * 32 + lg * 8];
        acc[rf][0] = __builtin_amdgcn_mfma_f32_16x16x32_bf16(a, w1[ks][0], acc[rf][0], 0, 0, 0);
        acc[rf][1] = __builtin_amdgcn_mfma_f32_16x16x32_bf16(a, w1[ks][1], acc[rf][1], 0, 0, 0);
      }
    }

#pragma unroll
    for (int rf = 0; rf < 4; ++rf)
#pragma unroll
      for (int cf = 0; cf < 2; ++cf)
#pragma unroll
        for (int j = 0; j < 4; ++j) {
          float hv = acc[rf][cf][j] + bias1[cf];
          hv = hv > 0.f ? hv : 0.f;
          Hs[rf * 16 + lg * 4 + j][wc + cf * 16 + l15] = f2bf(hv);
        }

    bar_lgkm();                               // Hs ready; X(t) consumed

#pragma unroll
    for (int rf = 0; rf < 4; ++rf)
#pragma unroll
      for (int cf = 0; cf < 2; ++cf)
#pragma unroll
        for (int j = 0; j < 4; ++j) acc[rf][cf][j] = 0.f;

    // layer 2: [64,128] @ [128,128]
#pragma unroll
    for (int ks = 0; ks < 4; ++ks) {
#pragma unroll
      for (int rf = 0; rf < 4; ++rf) {
        bf16x8 a = *(const bf16x8*)&Hs[rf * 16 + l15][ks * 32 + lg * 8];
        acc[rf][0] = __builtin_amdgcn_mfma_f32_16x16x32_bf16(a, w2[ks][0], acc[rf][0], 0, 0, 0);
        acc[rf][1] = __builtin_amdgcn_mfma_f32_16x16x32_bf16(a, w2[ks][1], acc[rf][1], 0, 0, 0);
      }
    }

    bar_lgkm();                               // Hs consumed -> OT region free

#pragma unroll
    for (int rf = 0; rf < 4; ++rf) {
#pragma unroll
      for (int cf = 0; cf < 2; ++cf) {
#pragma unroll
        for (int j = 0; j < 4; ++j) {
          float v = acc[rf][cf][j] + bias2[cf];
          OT[rf * 16 + lg * 4 + j][wc + cf * 16 + l15] = v;
          if (cf == 0) es0 += v; else es1 += v;
        }
      }
    }

    bar_lgkm();                               // OT ready

    // coalesced store: 1KB contiguous per wave-instruction
    {
      long e0c = t * 64;
#pragma unroll
      for (int i = 0; i < 8; ++i) {
        int ch = tid + i * 256;
        int r = ch >> 5, c4 = ch & 31;
        float4 f = *(const float4*)&OT[r][c4 * 4];
        *(float4*)(e_out + (e0c + r) * H + c4 * 4) = f;
      }
    }

    bar_lgkm();                               // OT reads done -> X region writable

    if (hasN1) WRITE_X();                     // consume in-flight gathers (t+EGRID)
    if (hasN2) IDX_WRITE(ti & 1);
    bar_lgkm();                               // X(t+EGRID) + idx published

    if (hasN2) ISSUE(t + 2 * EGRID, ti & 1);  // next gathers; in flight across next iter
  }

#pragma unroll
  for (int m = 16; m < 64; m <<= 1) { es0 += __shfl_xor(es0, m); es1 += __shfl_xor(es1, m); }
  if (lane < 16) {
    atomicAdd(&esum_p[(wc + lane) * 16], es0);
    atomicAdd(&esum_p[(wc + 16 + lane) * 16], es1);
  }
}

// ---------------- node kernel: 64 nodes/block; CSR gather-aggregate, no atomics ---
__global__ __launch_bounds__(256, 3) void node_kernel(
    const float* __restrict__ node_attr, const float* __restrict__ uattr,
    const int* __restrict__ node_idx, const u16* __restrict__ wbuf,
    const float* __restrict__ b1, const float* __restrict__ b2,
    const float* __restrict__ e_out, const int* __restrict__ offsets,
    const int* __restrict__ cursor, const int* __restrict__ bucket,
    float* __restrict__ v_out, float* __restrict__ vsum_p)
{
  __shared__ __align__(16) u16 X[64][232];    // 224 cols + pad
  __shared__ __align__(16) u16 Hs[64][136];

  const int tid = threadIdx.x;
  const int wave = tid >> 6, lane = tid & 63;
  const int l15 = lane & 15, lg = lane >> 4;
  const long n0 = (long)blockIdx.x * 64;
  const int wc = wave * 32;

  // ---- CSR gather: 4 threads per node, 2-edge unrolled for MLP ----
  {
    int gr = tid >> 2, gq = tid & 3;
    long gn = n0 + gr;
    float a[32];
#pragma unroll
    for (int k = 0; k < 32; ++k) a[k] = 0.f;
    if (gn < N_NODES) {
      int s = offsets[gn], e = cursor[gn];     // cursor == row end after fill
      int i = s;
      for (; i + 2 <= e; i += 2) {
        int e0 = bucket[i], e1 = bucket[i + 1];
        const float* p0 = e_out + (long)e0 * H + gq * 32;
        const float* p1 = e_out + (long)e1 * H + gq * 32;
        float4 f0[8], f1[8];
#pragma unroll
        for (int k = 0; k < 8; ++k) f0[k] = *(const float4*)(p0 + k * 4);
#pragma unroll
        for (int k = 0; k < 8; ++k) f1[k] = *(const float4*)(p1 + k * 4);
#pragma unroll
        for (int k = 0; k < 8; ++k) {
          a[k * 4 + 0] += f0[k].x + f1[k].x;
          a[k * 4 + 1] += f0[k].y + f1[k].y;
          a[k * 4 + 2] += f0[k].z + f1[k].z;
          a[k * 4 + 3] += f0[k].w + f1[k].w;
        }
      }
      if (i < e) {
        int e0 = bucket[i];
        const float* p0 = e_out + (long)e0 * H + gq * 32;
#pragma unroll
        for (int k = 0; k < 8; ++k) {
          float4 f = *(const float4*)(p0 + k * 4);
          a[k * 4 + 0] += f.x; a[k * 4 + 1] += f.y;
          a[k * 4 + 2] += f.z; a[k * 4 + 3] += f.w;
        }
      }
    }
#pragma unroll
    for (int k = 0; k < 4; ++k) {
      u16x8 pk;
#pragma unroll
      for (int j = 0; j < 8; ++j) pk[j] = f2bf(a[k * 8 + j]);
      *(u16x8*)&X[gr][64 + gq * 32 + k * 8] = pk;
    }
  }

  // ---- stage node_attr (cols 0..63) and u (cols 192..223) ----
#pragma unroll
  for (int it = 0; it < 3; ++it) {
    int ch = tid + it * 256;
    int r = ch / 12, seg = ch - r * 12;
    long n = n0 + r; if (n >= N_NODES) n = N_NODES - 1;
    const float* src;
    int col;
    if (seg < 8) { col = seg * 8;             src = node_attr + n * DV + col; }
    else         { col = 192 + (seg - 8) * 8; src = uattr + (long)node_idx[n] * DU + (seg - 8) * 8; }
    float4 f0 = *(const float4*)src;
    float4 f1 = *(const float4*)(src + 4);
    u16x8 p;
    p[0] = f2bf(f0.x); p[1] = f2bf(f0.y); p[2] = f2bf(f0.z); p[3] = f2bf(f0.w);
    p[4] = f2bf(f1.x); p[5] = f2bf(f1.y); p[6] = f2bf(f1.z); p[7] = f2bf(f1.w);
    *(u16x8*)&X[r][col] = p;
  }

  // per-wave weight slices
  bf16x8 w1[7][2], w2[4][2];
  {
    const u16* w1t = wbuf + W1NT_OFF;
    const u16* w2t = wbuf + W2NT_OFF;
#pragma unroll
    for (int cf = 0; cf < 2; ++cf) {
      const u16* p1 = w1t + (wc + cf * 16 + l15) * 224 + lg * 8;
#pragma unroll
      for (int ks = 0; ks < 7; ++ks) w1[ks][cf] = *(const bf16x8*)(p1 + ks * 32);
      const u16* p2 = w2t + (wc + cf * 16 + l15) * 128 + lg * 8;
#pragma unroll
      for (int ks = 0; ks < 4; ++ks) w2[ks][cf] = *(const bf16x8*)(p2 + ks * 32);
    }
  }

  __syncthreads();

  f32x4 acc[4][2];
#pragma unroll
  for (int rf = 0; rf < 4; ++rf)
#pragma unroll
    for (int cf = 0; cf < 2; ++cf)
#pragma unroll
      for (int j = 0; j < 4; ++j) acc[rf][cf][j] = 0.f;

#pragma unroll
  for (int ks = 0; ks < 7; ++ks) {
#pragma unroll
    for (int rf = 0; rf < 4; ++rf) {
      bf16x8 a = *(const bf16x8*)&X[rf * 16 + l15][ks * 32 + lg * 8];
      acc[rf][0] = __builtin_amdgcn_mfma_f32_16x16x32_bf16(a, w1[ks][0], acc[rf][0], 0, 0, 0);
      acc[rf][1] = __builtin_amdgcn_mfma_f32_16x16x32_bf16(a, w1[ks][1], acc[rf][1], 0, 0, 0);
    }
  }

  float bias1[2] = { b1[wc + l15], b1[wc + 16 + l15] };
#pragma unroll
  for (int rf = 0; rf < 4; ++rf)
#pragma unroll
    for (int cf = 0; cf < 2; ++cf)
#pragma unroll
      for (int j = 0; j < 4; ++j) {
        float hv = acc[rf][cf][j] + bias1[cf];
        hv = hv > 0.f ? hv : 0.f;
        Hs[rf * 16 + lg * 4 + j][wc + cf * 16 + l15] = f2bf(hv);
      }

  __syncthreads();

#pragma unroll
  for (int rf = 0; rf < 4; ++rf)
#pragma unroll
    for (int cf = 0; cf < 2; ++cf)
#pragma unroll
      for (int j = 0; j < 4; ++j) acc[rf][cf][j] = 0.f;

#pragma unroll
  for (int ks = 0; ks < 4; ++ks) {
#pragma unroll
    for (int rf = 0; rf < 4; ++rf) {
      bf16x8 a = *(const bf16x8*)&Hs[rf * 16 + l15][ks * 32 + lg * 8];
      acc[rf][0] = __builtin_amdgcn_mfma_f32_16x16x32_bf16(a, w2[ks][0], acc[rf][0], 0, 0, 0);
      acc[rf][1] = __builtin_amdgcn_mfma_f32_16x16x32_bf16(a, w2[ks][1], acc[rf][1], 0, 0, 0);
    }
  }

  float bias2[2] = { b2[wc + l15], b2[wc + 16 + l15] };
  float vs0 = 0.f, vs1 = 0.f;
#pragma unroll
  for (int rf = 0; rf < 4; ++rf) {
#pragma unroll
    for (int cf = 0; cf < 2; ++cf) {
      int colg = wc + cf * 16 + l15;
#pragma unroll
      for (int j = 0; j < 4; ++j) {
        int r = rf * 16 + lg * 4 + j;
        long n = n0 + r;
        if (n < N_NODES) {
          float v = acc[rf][cf][j] + bias2[cf];
          v_out[n * H + colg] = v;
          if (cf == 0) vs0 += v; else vs1 += v;
        }
      }
    }
  }
#pragma unroll
  for (int m = 16; m < 64; m <<= 1) { vs0 += __shfl_xor(vs0, m); vs1 += __shfl_xor(vs1, m); }
  if (lane < 16) {
    atomicAdd(&vsum_p[(wc + lane) * 16], vs0);
    atomicAdd(&vsum_p[(wc + 16 + lane) * 16], vs1);
  }
}

// ---------------- global kernel: G=1, f32 precision ----------------
__global__ void global_kernel(const float* __restrict__ uattr,
    const float* __restrict__ W1g, const float* __restrict__ b1g,
    const float* __restrict__ W2g, const float* __restrict__ b2g,
    const float* __restrict__ esum_p, const float* __restrict__ vsum_p,
    float* __restrict__ g_out)
{
  __shared__ float gin[288];
  __shared__ float hbuf[128];
  int t = threadIdx.x;   // 128 threads
  gin[t]       = vsum_p[t * 16] * (1.f / (float)N_NODES);
  gin[128 + t] = esum_p[t * 16] * (1.f / (float)N_EDGES);
  if (t < 32) gin[256 + t] = uattr[t];
  __syncthreads();
  float a = b1g[t];
  for (int k = 0; k < 288; ++k) a += gin[k] * W1g[k * H + t];
  hbuf[t] = fmaxf(a, 0.f);
  __syncthreads();
  float b = b2g[t];
  for (int k = 0; k < 128; ++k) b += hbuf[k] * W2g[k * H + t];
  g_out[t] = b;
}

extern "C" void kernel_launch(void* const* d_in, const int* in_sizes, int n_in,
                              void* d_out, int out_size, void* d_ws, size_t ws_size,
                              hipStream_t stream) {
  const float* node_attr = (const float*)d_in[0];
  const int*   edges     = (const int*)d_in[1];
  const float* edge_attr = (const float*)d_in[2];
  const float* uattr     = (const float*)d_in[3];
  const int*   node_idx  = (const int*)d_in[4];
  const int*   edge_idx  = (const int*)d_in[5];
  const float* W1e = (const float*)d_in[6];  const float* b1e = (const float*)d_in[7];
  const float* W2e = (const float*)d_in[8];  const float* b2e = (const float*)d_in[9];
  const float* W1n = (const float*)d_in[10]; const float* b1n = (const float*)d_in[11];
  const float* W2n = (const float*)d_in[12]; const float* b2n = (const float*)d_in[13];
  const float* W1g = (const float*)d_in[14]; const float* b1g = (const float*)d_in[15];
  const float* W2g = (const float*)d_in[16]; const float* b2g = (const float*)d_in[17];

  float* out   = (float*)d_out;
  float* v_out = out;                                          // [N,H]
  float* e_out = out + (long)N_NODES * H;                      // [E,H]
  float* g_out = out + (long)N_NODES * H + (long)N_EDGES * H;  // [G,H]

  char* ws = (char*)d_ws;
  float* esum_p = (float*)(ws + OFF_ESUM);
  float* vsum_p = (float*)(ws + OFF_VSUM);
  int*   part   = (int*)(ws + OFF_PART);
  u16*   wbuf   = (u16*)(ws + OFF_WBUF);
  int*   deg    = (int*)(ws + OFF_DEG);     // becomes cursor after scan_down
  int*   offs   = (int*)(ws + OFF_OFFS);
  int*   buck   = (int*)(ws + OFF_BUCK);

  hipMemsetAsync(ws, 0, 16384, stream);                  // esum_p + vsum_p
  hipMemsetAsync(deg, 0, N_NODES * sizeof(int), stream); // degrees

  prep_weights<<<WBUF_ELEMS / 256, 256, 0, stream>>>(W1e, W2e, W1n, W2n, wbuf);
  degree_kernel<<<(N_EDGES + 255) / 256, 256, 0, stream>>>(edges, deg);
  scan_part<<<NPART, 256, 0, stream>>>(deg, part);
  scan_top<<<1, 512, 0, stream>>>(part);
  scan_down<<<NPART, 256, 0, stream>>>(part, deg, offs);
  fill_kernel<<<(N_EDGES + 255) / 256, 256, 0, stream>>>(edges, deg, buck);

  edge_kernel<<<EGRID, 256, 0, stream>>>(node_attr, edges, edge_attr, uattr,
                                         edge_idx, wbuf, b1e, b2e,
                                         e_out, esum_p);
  node_kernel<<<(N_NODES + 63) / 64, 256, 0, stream>>>(node_attr, uattr, node_idx,
                                                       wbuf, b1n, b2n,
                                                       e_out, offs, deg, buck,
                                                       v_out, vsum_p);
  global_kernel<<<1, 128, 0, stream>>>(uattr, W1g, b1g, W2g, b2g, esum_p, vsum_p, g_out);
}